// Round 6
// baseline (1010.013 us; speedup 1.0000x reference)
//
#include <hip/hip_runtime.h>
#include <math.h>

#define NNODES 100000

__device__ __forceinline__ float lrelu(float v) { return v > 0.f ? v : 0.2f * v; }

// XOR swizzle for row-major LDS A-tiles: flips k bits 2-4. Reads with the same
// formula are conflict-free because (row>>3) spreads the 8 rows of a thread's
// fragment across 8 bank-groups.
#define SWZ(row) ((((row) & 3) ^ (((row) >> 3) & 7)) << 2)

// ---------------- GEMM1: h1[N,64] = x[N,512] @ W1[512,64] ----------------
// 128 threads, tile 128 rows x 64 cols, per-thread 8x8 (cols tx*4 and 32+tx*4).
// xs row-major swizzled; A-frags read ALONG k as b128.
__global__ __launch_bounds__(128) void gemm1_k(const float* __restrict__ x,
                                               const float* __restrict__ W,
                                               float* __restrict__ h1, int Nn) {
    __shared__ float xs[128][64];
    __shared__ float ws[64][64];
    int r0 = blockIdx.x * 128;
    int t = threadIdx.x;
    int ty = t >> 3, tx = t & 7;  // 16 x 8
    float acc0[8][4] = {};
    float acc1[8][4] = {};
    for (int kb = 0; kb < 512; kb += 64) {
        // stage x tile: 128 rows x 64 k = 2048 float4
        for (int l = t; l < 2048; l += 128) {
            int row = l >> 4;
            int c4 = (l & 15) << 2;
            int gr = r0 + row;
            float4 v = make_float4(0.f, 0.f, 0.f, 0.f);
            if (gr < Nn) v = *reinterpret_cast<const float4*>(&x[(size_t)gr * 512 + kb + c4]);
            *reinterpret_cast<float4*>(&xs[row][c4 ^ SWZ(row)]) = v;
        }
        // stage W tile: 64 k x 64 cols = 1024 float4 (plain row-major)
        for (int l = t; l < 1024; l += 128) {
            int row = l >> 4;
            int c4 = (l & 15) << 2;
            *reinterpret_cast<float4*>(&ws[row][c4]) =
                *reinterpret_cast<const float4*>(&W[(size_t)(kb + row) * 64 + c4]);
        }
        __syncthreads();
#pragma unroll 1
        for (int k0 = 0; k0 < 64; k0 += 4) {
            float4 av[8];
#pragma unroll
            for (int i = 0; i < 8; ++i) {
                int row = ty * 8 + i;
                av[i] = *reinterpret_cast<const float4*>(&xs[row][k0 ^ SWZ(row)]);
            }
            float4 b0[4], b1[4];
#pragma unroll
            for (int kk = 0; kk < 4; ++kk) {
                b0[kk] = *reinterpret_cast<const float4*>(&ws[k0 + kk][tx * 4]);
                b1[kk] = *reinterpret_cast<const float4*>(&ws[k0 + kk][32 + tx * 4]);
            }
#pragma unroll
            for (int kk = 0; kk < 4; ++kk) {
#pragma unroll
                for (int i = 0; i < 8; ++i) {
                    float a = (kk == 0) ? av[i].x : (kk == 1) ? av[i].y : (kk == 2) ? av[i].z : av[i].w;
                    acc0[i][0] += a * b0[kk].x; acc0[i][1] += a * b0[kk].y;
                    acc0[i][2] += a * b0[kk].z; acc0[i][3] += a * b0[kk].w;
                    acc1[i][0] += a * b1[kk].x; acc1[i][1] += a * b1[kk].y;
                    acc1[i][2] += a * b1[kk].z; acc1[i][3] += a * b1[kk].w;
                }
            }
        }
        __syncthreads();
    }
#pragma unroll
    for (int i = 0; i < 8; ++i) {
        int gr = r0 + ty * 8 + i;
        if (gr < Nn) {
            *reinterpret_cast<float4*>(&h1[(size_t)gr * 64 + tx * 4]) =
                make_float4(acc0[i][0], acc0[i][1], acc0[i][2], acc0[i][3]);
            *reinterpret_cast<float4*>(&h1[(size_t)gr * 64 + 32 + tx * 4]) =
                make_float4(acc1[i][0], acc1[i][1], acc1[i][2], acc1[i][3]);
        }
    }
}

// ---------------- GEMM2: h2[N,128] = h1a[N,64] @ W2[64,128] ----------------
// 256 threads, tile 128 rows x 128 cols, per-thread 8x8 (cols tx*4, 64+tx*4).
__global__ __launch_bounds__(256) void gemm2_k(const float* __restrict__ xin,
                                               const float* __restrict__ W,
                                               float* __restrict__ h2, int Nn) {
    __shared__ float xs[128][64];
    __shared__ float ws[64][128];
    int r0 = blockIdx.x * 128;
    int t = threadIdx.x;
    int ty = t >> 4, tx = t & 15;  // 16 x 16
    // stage xin tile: 128 rows x 64 k = 2048 float4
    for (int l = t; l < 2048; l += 256) {
        int row = l >> 4;
        int c4 = (l & 15) << 2;
        int gr = r0 + row;
        float4 v = make_float4(0.f, 0.f, 0.f, 0.f);
        if (gr < Nn) v = *reinterpret_cast<const float4*>(&xin[(size_t)gr * 64 + c4]);
        *reinterpret_cast<float4*>(&xs[row][c4 ^ SWZ(row)]) = v;
    }
    // stage W2: 64 x 128 = 2048 float4
    for (int l = t; l < 2048; l += 256) {
        int row = l >> 5;
        int c4 = (l & 31) << 2;
        *reinterpret_cast<float4*>(&ws[row][c4]) =
            *reinterpret_cast<const float4*>(&W[(size_t)row * 128 + c4]);
    }
    __syncthreads();
    float acc0[8][4] = {};
    float acc1[8][4] = {};
#pragma unroll 1
    for (int k0 = 0; k0 < 64; k0 += 4) {
        float4 av[8];
#pragma unroll
        for (int i = 0; i < 8; ++i) {
            int row = ty * 8 + i;
            av[i] = *reinterpret_cast<const float4*>(&xs[row][k0 ^ SWZ(row)]);
        }
        float4 b0[4], b1[4];
#pragma unroll
        for (int kk = 0; kk < 4; ++kk) {
            b0[kk] = *reinterpret_cast<const float4*>(&ws[k0 + kk][tx * 4]);
            b1[kk] = *reinterpret_cast<const float4*>(&ws[k0 + kk][64 + tx * 4]);
        }
#pragma unroll
        for (int kk = 0; kk < 4; ++kk) {
#pragma unroll
            for (int i = 0; i < 8; ++i) {
                float a = (kk == 0) ? av[i].x : (kk == 1) ? av[i].y : (kk == 2) ? av[i].z : av[i].w;
                acc0[i][0] += a * b0[kk].x; acc0[i][1] += a * b0[kk].y;
                acc0[i][2] += a * b0[kk].z; acc0[i][3] += a * b0[kk].w;
                acc1[i][0] += a * b1[kk].x; acc1[i][1] += a * b1[kk].y;
                acc1[i][2] += a * b1[kk].z; acc1[i][3] += a * b1[kk].w;
            }
        }
    }
#pragma unroll
    for (int i = 0; i < 8; ++i) {
        int gr = r0 + ty * 8 + i;
        if (gr < Nn) {
            *reinterpret_cast<float4*>(&h2[(size_t)gr * 128 + tx * 4]) =
                make_float4(acc0[i][0], acc0[i][1], acc0[i][2], acc0[i][3]);
            *reinterpret_cast<float4*>(&h2[(size_t)gr * 128 + 64 + tx * 4]) =
                make_float4(acc1[i][0], acc1[i][1], acc1[i][2], acc1[i][3]);
        }
    }
}

// ---------------- attn coef layer 1: as1/ad1 [N,8] ----------------
__global__ __launch_bounds__(256) void attn1_k(const float* __restrict__ h1,
                                               const float* __restrict__ asrc,
                                               const float* __restrict__ adst,
                                               float* __restrict__ as1,
                                               float* __restrict__ ad1, int Nn) {
    int t = blockIdx.x * 256 + threadIdx.x;
    int n = t >> 3, h = t & 7;
    if (n >= Nn) return;
    const float* hp = h1 + (size_t)n * 64 + h * 8;
    float s = 0.f, d = 0.f;
#pragma unroll
    for (int c = 0; c < 8; ++c) {
        float v = hp[c];
        s += v * asrc[h * 8 + c];
        d += v * adst[h * 8 + c];
    }
    as1[(size_t)n * 8 + h] = s;
    ad1[(size_t)n * 8 + h] = d;
}

// ---------------- attn coef layer 2: as2/ad2 [N] ----------------
__global__ __launch_bounds__(256) void attn2_k(const float* __restrict__ h2,
                                               const float* __restrict__ asrc,
                                               const float* __restrict__ adst,
                                               float* __restrict__ as2,
                                               float* __restrict__ ad2, int Nn) {
    int wid = threadIdx.x >> 6, lane = threadIdx.x & 63;
    int n = blockIdx.x * 4 + wid;
    if (n >= Nn) return;
    float v0 = h2[(size_t)n * 128 + lane];
    float v1 = h2[(size_t)n * 128 + 64 + lane];
    float s = v0 * asrc[lane] + v1 * asrc[64 + lane];
    float d = v0 * adst[lane] + v1 * adst[64 + lane];
#pragma unroll
    for (int off = 32; off >= 1; off >>= 1) {
        s += __shfl_xor(s, off);
        d += __shfl_xor(d, off);
    }
    if (lane == 0) { as2[n] = s; ad2[n] = d; }
}

// ---------------- CSR build ----------------
__global__ __launch_bounds__(256) void hist_k(const int* __restrict__ ei, int E, int Etot,
                                              int* __restrict__ indeg) {
    int e = blockIdx.x * 256 + threadIdx.x;
    if (e >= Etot) return;
    int d = (e < E) ? ei[E + e] : (e - E);
    atomicAdd(&indeg[d], 1);
}

__global__ __launch_bounds__(256) void scanA_k(const int* __restrict__ indeg,
                                               int* __restrict__ indptr,
                                               int* __restrict__ bsums, int Nn) {
    __shared__ int sd[256];
    int t = threadIdx.x;
    int i0 = blockIdx.x * 2048 + t * 8;
    int v[8], ex[8];
    int run = 0;
#pragma unroll
    for (int j = 0; j < 8; ++j) {
        int i = i0 + j;
        v[j] = (i < Nn) ? indeg[i] : 0;
        ex[j] = run;
        run += v[j];
    }
    sd[t] = run;
    __syncthreads();
    for (int off = 1; off < 256; off <<= 1) {
        int a = (t >= off) ? sd[t - off] : 0;
        __syncthreads();
        sd[t] += a;
        __syncthreads();
    }
    int texc = sd[t] - run;
#pragma unroll
    for (int j = 0; j < 8; ++j) {
        int i = i0 + j;
        if (i < Nn) indptr[i] = texc + ex[j];
    }
    if (t == 0) bsums[blockIdx.x] = sd[255];
}

__global__ void scanB_k(int* __restrict__ bsums, int nb) {
    if (threadIdx.x == 0 && blockIdx.x == 0) {
        int run = 0;
        for (int b = 0; b < nb; ++b) {
            int x = bsums[b];
            bsums[b] = run;
            run += x;
        }
    }
}

__global__ __launch_bounds__(256) void scanC_k(int* __restrict__ indptr,
                                               const int* __restrict__ bsums,
                                               int* __restrict__ cursor, int Nn, int Etot) {
    int t = threadIdx.x;
    int b = blockIdx.x;
    int base = bsums[b];
    int i0 = b * 2048 + t * 8;
#pragma unroll
    for (int j = 0; j < 8; ++j) {
        int i = i0 + j;
        if (i < Nn) {
            int val = indptr[i] + base;
            indptr[i] = val;
            cursor[i] = val;
        }
    }
    if (b == 0 && t == 0) indptr[Nn] = Etot;
}

__global__ __launch_bounds__(256) void fill_k(const int* __restrict__ ei, int E, int Etot,
                                              int* __restrict__ cursor, int* __restrict__ col) {
    int e = blockIdx.x * 256 + threadIdx.x;
    if (e >= Etot) return;
    int s, d;
    if (e < E) { s = ei[e]; d = ei[E + e]; }
    else { s = e - E; d = e - E; }
    int pos = atomicAdd(&cursor[d], 1);
    col[pos] = s;
}

// ---------------- aggregation layer 1 (8 heads x 8 ch) + bias + ELU ----------------
__global__ __launch_bounds__(256) void agg1_k(const float* __restrict__ h1,
                                              const float* __restrict__ as1,
                                              const float* __restrict__ ad1,
                                              const int* __restrict__ indptr,
                                              const int* __restrict__ col,
                                              const float* __restrict__ b1,
                                              float* __restrict__ h1a, int Nn) {
    int wid = threadIdx.x >> 6, lane = threadIdx.x & 63;
    int n = blockIdx.x * 4 + wid;
    if (n >= Nn) return;
    int beg = indptr[n], end = indptr[n + 1];
    int h = lane & 7, eo = lane >> 3;
    float adn = ad1[(size_t)n * 8 + h];
    float ss = 0.f;
    for (int i = beg + eo; i < end; i += 8) {
        int s = col[i];
        ss += __expf(lrelu(as1[(size_t)s * 8 + h] + adn));
    }
    ss += __shfl_xor(ss, 8);
    ss += __shfl_xor(ss, 16);
    ss += __shfl_xor(ss, 32);
    int hb = lane >> 3;
    float sb = __shfl(ss, hb);
    float ab = __shfl(adn, hb);
    float inv = 1.f / sb;
    const float* __restrict__ h1l = h1 + lane;
    float acc0 = 0.f, acc1 = 0.f, acc2 = 0.f, acc3 = 0.f;
    float acc4 = 0.f, acc5 = 0.f, acc6 = 0.f, acc7 = 0.f;
    int i = beg;
    for (; i + 8 <= end; i += 8) {
        int s0 = col[i], s1 = col[i + 1], s2 = col[i + 2], s3 = col[i + 3];
        int s4 = col[i + 4], s5 = col[i + 5], s6 = col[i + 6], s7 = col[i + 7];
        float w0 = __expf(lrelu(as1[(size_t)s0 * 8 + hb] + ab));
        float w1 = __expf(lrelu(as1[(size_t)s1 * 8 + hb] + ab));
        float w2 = __expf(lrelu(as1[(size_t)s2 * 8 + hb] + ab));
        float w3 = __expf(lrelu(as1[(size_t)s3 * 8 + hb] + ab));
        float w4 = __expf(lrelu(as1[(size_t)s4 * 8 + hb] + ab));
        float w5 = __expf(lrelu(as1[(size_t)s5 * 8 + hb] + ab));
        float w6 = __expf(lrelu(as1[(size_t)s6 * 8 + hb] + ab));
        float w7 = __expf(lrelu(as1[(size_t)s7 * 8 + hb] + ab));
        acc0 += w0 * h1l[(size_t)s0 * 64];
        acc1 += w1 * h1l[(size_t)s1 * 64];
        acc2 += w2 * h1l[(size_t)s2 * 64];
        acc3 += w3 * h1l[(size_t)s3 * 64];
        acc4 += w4 * h1l[(size_t)s4 * 64];
        acc5 += w5 * h1l[(size_t)s5 * 64];
        acc6 += w6 * h1l[(size_t)s6 * 64];
        acc7 += w7 * h1l[(size_t)s7 * 64];
    }
    for (; i < end; ++i) {
        int s = col[i];
        acc0 += __expf(lrelu(as1[(size_t)s * 8 + hb] + ab)) * h1l[(size_t)s * 64];
    }
    float o = (((acc0 + acc1) + (acc2 + acc3)) + ((acc4 + acc5) + (acc6 + acc7))) * inv + b1[lane];
    h1a[(size_t)n * 64 + lane] = o > 0.f ? o : expm1f(o);
}

// ---------------- aggregation layer 2 (1 head x 128 ch) + bias ----------------
__global__ __launch_bounds__(256) void agg2_k(const float* __restrict__ h2,
                                              const float* __restrict__ as2,
                                              const float* __restrict__ ad2,
                                              const int* __restrict__ indptr,
                                              const int* __restrict__ col,
                                              const float* __restrict__ b2,
                                              float* __restrict__ out, int Nn) {
    int wid = threadIdx.x >> 6, lane = threadIdx.x & 63;
    int n = blockIdx.x * 4 + wid;
    if (n >= Nn) return;
    int beg = indptr[n], end = indptr[n + 1];
    float adn = ad2[n];
    float ss = 0.f;
    for (int i = beg + lane; i < end; i += 64) {
        ss += __expf(lrelu(as2[col[i]] + adn));
    }
#pragma unroll
    for (int off = 32; off >= 1; off >>= 1) ss += __shfl_xor(ss, off);
    float inv = 1.f / ss;
    const float* __restrict__ h2l = h2 + lane;
    float a00 = 0.f, a01 = 0.f, a02 = 0.f, a03 = 0.f;
    float a04 = 0.f, a05 = 0.f, a06 = 0.f, a07 = 0.f;
    float a10 = 0.f, a11 = 0.f, a12 = 0.f, a13 = 0.f;
    float a14 = 0.f, a15 = 0.f, a16 = 0.f, a17 = 0.f;
    int i = beg;
    for (; i + 8 <= end; i += 8) {
        int s0 = col[i], s1 = col[i + 1], s2 = col[i + 2], s3 = col[i + 3];
        int s4 = col[i + 4], s5 = col[i + 5], s6 = col[i + 6], s7 = col[i + 7];
        float w0 = __expf(lrelu(as2[s0] + adn));
        float w1 = __expf(lrelu(as2[s1] + adn));
        float w2 = __expf(lrelu(as2[s2] + adn));
        float w3 = __expf(lrelu(as2[s3] + adn));
        float w4 = __expf(lrelu(as2[s4] + adn));
        float w5 = __expf(lrelu(as2[s5] + adn));
        float w6 = __expf(lrelu(as2[s6] + adn));
        float w7 = __expf(lrelu(as2[s7] + adn));
        a00 += w0 * h2l[(size_t)s0 * 128]; a10 += w0 * h2l[(size_t)s0 * 128 + 64];
        a01 += w1 * h2l[(size_t)s1 * 128]; a11 += w1 * h2l[(size_t)s1 * 128 + 64];
        a02 += w2 * h2l[(size_t)s2 * 128]; a12 += w2 * h2l[(size_t)s2 * 128 + 64];
        a03 += w3 * h2l[(size_t)s3 * 128]; a13 += w3 * h2l[(size_t)s3 * 128 + 64];
        a04 += w4 * h2l[(size_t)s4 * 128]; a14 += w4 * h2l[(size_t)s4 * 128 + 64];
        a05 += w5 * h2l[(size_t)s5 * 128]; a15 += w5 * h2l[(size_t)s5 * 128 + 64];
        a06 += w6 * h2l[(size_t)s6 * 128]; a16 += w6 * h2l[(size_t)s6 * 128 + 64];
        a07 += w7 * h2l[(size_t)s7 * 128]; a17 += w7 * h2l[(size_t)s7 * 128 + 64];
    }
    for (; i < end; ++i) {
        int s = col[i];
        float w = __expf(lrelu(as2[s] + adn));
        a00 += w * h2l[(size_t)s * 128];
        a10 += w * h2l[(size_t)s * 128 + 64];
    }
    float r0 = ((a00 + a01) + (a02 + a03)) + ((a04 + a05) + (a06 + a07));
    float r1 = ((a10 + a11) + (a12 + a13)) + ((a14 + a15) + (a16 + a17));
    out[(size_t)n * 128 + lane] = r0 * inv + b2[lane];
    out[(size_t)n * 128 + 64 + lane] = r1 * inv + b2[64 + lane];
}

extern "C" void kernel_launch(void* const* d_in, const int* in_sizes, int n_in,
                              void* d_out, int out_size, void* d_ws, size_t ws_size,
                              hipStream_t stream) {
    const float* x = (const float*)d_in[0];
    const int* ei = (const int*)d_in[1];
    const float* W1 = (const float*)d_in[2];
    const float* asrc1 = (const float*)d_in[3];
    const float* adst1 = (const float*)d_in[4];
    const float* b1 = (const float*)d_in[5];
    const float* W2 = (const float*)d_in[6];
    const float* asrc2 = (const float*)d_in[7];
    const float* adst2 = (const float*)d_in[8];
    const float* b2 = (const float*)d_in[9];
    float* out = (float*)d_out;

    const int Nn = NNODES;
    const int E = in_sizes[1] / 2;
    const int Etot = E + Nn;

    char* w = (char*)d_ws;
    auto alloc = [&](size_t bytes) {
        char* p = w;
        w += (bytes + 255) & ~(size_t)255;
        return p;
    };
    float* h1 = (float*)alloc((size_t)Nn * 64 * 4);
    float* h1a = (float*)alloc((size_t)Nn * 64 * 4);
    float* h2 = (float*)alloc((size_t)Nn * 128 * 4);
    float* as1 = (float*)alloc((size_t)Nn * 8 * 4);
    float* ad1 = (float*)alloc((size_t)Nn * 8 * 4);
    float* as2 = (float*)alloc((size_t)Nn * 4);
    float* ad2 = (float*)alloc((size_t)Nn * 4);
    int* indeg = (int*)alloc((size_t)(Nn + 1) * 4);
    int* indptr = (int*)alloc((size_t)(Nn + 1) * 4);
    int* cursor = (int*)alloc((size_t)Nn * 4);
    int* bsums = (int*)alloc(4096);
    int* col = (int*)alloc((size_t)Etot * 4);

    const int NBLK = (Nn + 2047) / 2048;

    hipMemsetAsync(indeg, 0, (size_t)Nn * 4, stream);
    gemm1_k<<<(Nn + 127) / 128, 128, 0, stream>>>(x, W1, h1, Nn);
    attn1_k<<<(Nn * 8 + 255) / 256, 256, 0, stream>>>(h1, asrc1, adst1, as1, ad1, Nn);
    hist_k<<<(Etot + 255) / 256, 256, 0, stream>>>(ei, E, Etot, indeg);
    scanA_k<<<NBLK, 256, 0, stream>>>(indeg, indptr, bsums, Nn);
    scanB_k<<<1, 64, 0, stream>>>(bsums, NBLK);
    scanC_k<<<NBLK, 256, 0, stream>>>(indptr, bsums, cursor, Nn, Etot);
    fill_k<<<(Etot + 255) / 256, 256, 0, stream>>>(ei, E, Etot, cursor, col);
    agg1_k<<<(Nn + 3) / 4, 256, 0, stream>>>(h1, as1, ad1, indptr, col, b1, h1a, Nn);
    gemm2_k<<<(Nn + 127) / 128, 256, 0, stream>>>(h1a, W2, h2, Nn);
    attn2_k<<<(Nn + 3) / 4, 256, 0, stream>>>(h2, asrc2, adst2, as2, ad2, Nn);
    agg2_k<<<(Nn + 3) / 4, 256, 0, stream>>>(h2, as2, ad2, indptr, col, b2, out, Nn);
}

// Round 7
// 882.970 us; speedup vs baseline: 1.1439x; 1.1439x over previous
//
#include <hip/hip_runtime.h>
#include <math.h>

#define NNODES 100000

__device__ __forceinline__ float lrelu(float v) { return v > 0.f ? v : 0.2f * v; }

// XOR swizzle for row-major LDS A-tiles (flips k bits 2-4). Proven 0-conflict
// in round 6. Reads of 8 rows (stride 8) land on 8 distinct bank-quads.
#define SWZ(row) ((((row) & 3) ^ (((row) >> 3) & 7)) << 2)

// ---------------- GEMM1: h1[N,64] = x[N,512] @ W1[512,64] ----------------
// 256 threads, tile 256x64, per-thread 8x8 (rows ty*8.., cols tx*8..).
// T14 pipeline: prefetch next K-tile to regs BEFORE compute, ds_write AFTER.
__global__ __launch_bounds__(256) void gemm1_k(const float* __restrict__ x,
                                               const float* __restrict__ W,
                                               float* __restrict__ h1, int Nn) {
    __shared__ float xs[256][64];  // 64 KB, swizzled rows
    __shared__ float ws[64][64];   // 16 KB
    int r0 = blockIdx.x * 256;
    int t = threadIdx.x;
    int ty = t >> 3, tx = t & 7;  // 32 row-strips x 8 col-strips
    float4 xr[16], wr[4];
    float acc[8][8] = {};

    // stage kb=0
#pragma unroll
    for (int n = 0; n < 16; ++n) {
        int l = t + n * 256;
        int row = l >> 4, c4 = (l & 15) << 2;
        int gr = r0 + row;
        xr[n] = make_float4(0.f, 0.f, 0.f, 0.f);
        if (gr < Nn) xr[n] = *reinterpret_cast<const float4*>(&x[(size_t)gr * 512 + c4]);
    }
#pragma unroll
    for (int n = 0; n < 4; ++n) {
        int l = t + n * 256;
        int row = l >> 4, c4 = (l & 15) << 2;
        wr[n] = *reinterpret_cast<const float4*>(&W[(size_t)row * 64 + c4]);
    }
#pragma unroll
    for (int n = 0; n < 16; ++n) {
        int l = t + n * 256;
        int row = l >> 4, c4 = (l & 15) << 2;
        *reinterpret_cast<float4*>(&xs[row][c4 ^ SWZ(row)]) = xr[n];
    }
#pragma unroll
    for (int n = 0; n < 4; ++n) {
        int l = t + n * 256;
        int row = l >> 4, c4 = (l & 15) << 2;
        *reinterpret_cast<float4*>(&ws[row][c4]) = wr[n];
    }
    __syncthreads();

    for (int kb = 0; kb < 512; kb += 64) {
        bool more = (kb + 64 < 512);
        if (more) {
            // prefetch kb+64 into regs; HBM latency hides under compute below
#pragma unroll
            for (int n = 0; n < 16; ++n) {
                int l = t + n * 256;
                int row = l >> 4, c4 = (l & 15) << 2;
                int gr = r0 + row;
                xr[n] = make_float4(0.f, 0.f, 0.f, 0.f);
                if (gr < Nn) xr[n] = *reinterpret_cast<const float4*>(&x[(size_t)gr * 512 + kb + 64 + c4]);
            }
#pragma unroll
            for (int n = 0; n < 4; ++n) {
                int l = t + n * 256;
                int row = l >> 4, c4 = (l & 15) << 2;
                wr[n] = *reinterpret_cast<const float4*>(&W[(size_t)(kb + 64 + row) * 64 + c4]);
            }
        }
#pragma unroll 1
        for (int k0 = 0; k0 < 64; k0 += 4) {
            float4 av[8], ba[4], bb[4];
#pragma unroll
            for (int i = 0; i < 8; ++i) {
                int row = ty * 8 + i;
                av[i] = *reinterpret_cast<const float4*>(&xs[row][k0 ^ SWZ(row)]);
            }
#pragma unroll
            for (int kk = 0; kk < 4; ++kk) {
                ba[kk] = *reinterpret_cast<const float4*>(&ws[k0 + kk][tx * 8]);
                bb[kk] = *reinterpret_cast<const float4*>(&ws[k0 + kk][tx * 8 + 4]);
            }
#pragma unroll
            for (int kk = 0; kk < 4; ++kk) {
#pragma unroll
                for (int i = 0; i < 8; ++i) {
                    float a = (kk == 0) ? av[i].x : (kk == 1) ? av[i].y : (kk == 2) ? av[i].z : av[i].w;
                    acc[i][0] += a * ba[kk].x; acc[i][1] += a * ba[kk].y;
                    acc[i][2] += a * ba[kk].z; acc[i][3] += a * ba[kk].w;
                    acc[i][4] += a * bb[kk].x; acc[i][5] += a * bb[kk].y;
                    acc[i][6] += a * bb[kk].z; acc[i][7] += a * bb[kk].w;
                }
            }
        }
        __syncthreads();
        if (more) {
#pragma unroll
            for (int n = 0; n < 16; ++n) {
                int l = t + n * 256;
                int row = l >> 4, c4 = (l & 15) << 2;
                *reinterpret_cast<float4*>(&xs[row][c4 ^ SWZ(row)]) = xr[n];
            }
#pragma unroll
            for (int n = 0; n < 4; ++n) {
                int l = t + n * 256;
                int row = l >> 4, c4 = (l & 15) << 2;
                *reinterpret_cast<float4*>(&ws[row][c4]) = wr[n];
            }
        }
        __syncthreads();
    }
#pragma unroll
    for (int i = 0; i < 8; ++i) {
        int gr = r0 + ty * 8 + i;
        if (gr < Nn) {
            *reinterpret_cast<float4*>(&h1[(size_t)gr * 64 + tx * 8]) =
                make_float4(acc[i][0], acc[i][1], acc[i][2], acc[i][3]);
            *reinterpret_cast<float4*>(&h1[(size_t)gr * 64 + tx * 8 + 4]) =
                make_float4(acc[i][4], acc[i][5], acc[i][6], acc[i][7]);
        }
    }
}

// ---------------- GEMM2: h2[N,128] = h1a[N,64] @ W2[64,128] ----------------
// 256 threads, tile 128x128, per-thread 8x8 (cols tx*4 and 64+tx*4, 2-way free).
// Single K-tile (K=64): stage once, compute.
__global__ __launch_bounds__(256) void gemm2_k(const float* __restrict__ xin,
                                               const float* __restrict__ W,
                                               float* __restrict__ h2, int Nn) {
    __shared__ float xs[128][64];   // 32 KB swizzled
    __shared__ float ws[64][128];   // 32 KB
    int r0 = blockIdx.x * 128;
    int t = threadIdx.x;
    int ty = t >> 4, tx = t & 15;  // 16 x 16
    for (int l = t; l < 2048; l += 256) {
        int row = l >> 4, c4 = (l & 15) << 2;
        int gr = r0 + row;
        float4 v = make_float4(0.f, 0.f, 0.f, 0.f);
        if (gr < Nn) v = *reinterpret_cast<const float4*>(&xin[(size_t)gr * 64 + c4]);
        *reinterpret_cast<float4*>(&xs[row][c4 ^ SWZ(row)]) = v;
    }
    for (int l = t; l < 2048; l += 256) {
        int row = l >> 5, c4 = (l & 31) << 2;
        *reinterpret_cast<float4*>(&ws[row][c4]) =
            *reinterpret_cast<const float4*>(&W[(size_t)row * 128 + c4]);
    }
    __syncthreads();
    float acc0[8][4] = {};
    float acc1[8][4] = {};
#pragma unroll 1
    for (int k0 = 0; k0 < 64; k0 += 4) {
        float4 av[8], ba[4], bb[4];
#pragma unroll
        for (int i = 0; i < 8; ++i) {
            int row = ty * 8 + i;
            av[i] = *reinterpret_cast<const float4*>(&xs[row][k0 ^ SWZ(row)]);
        }
#pragma unroll
        for (int kk = 0; kk < 4; ++kk) {
            ba[kk] = *reinterpret_cast<const float4*>(&ws[k0 + kk][tx * 4]);
            bb[kk] = *reinterpret_cast<const float4*>(&ws[k0 + kk][64 + tx * 4]);
        }
#pragma unroll
        for (int kk = 0; kk < 4; ++kk) {
#pragma unroll
            for (int i = 0; i < 8; ++i) {
                float a = (kk == 0) ? av[i].x : (kk == 1) ? av[i].y : (kk == 2) ? av[i].z : av[i].w;
                acc0[i][0] += a * ba[kk].x; acc0[i][1] += a * ba[kk].y;
                acc0[i][2] += a * ba[kk].z; acc0[i][3] += a * ba[kk].w;
                acc1[i][0] += a * bb[kk].x; acc1[i][1] += a * bb[kk].y;
                acc1[i][2] += a * bb[kk].z; acc1[i][3] += a * bb[kk].w;
            }
        }
    }
#pragma unroll
    for (int i = 0; i < 8; ++i) {
        int gr = r0 + ty * 8 + i;
        if (gr < Nn) {
            *reinterpret_cast<float4*>(&h2[(size_t)gr * 128 + tx * 4]) =
                make_float4(acc0[i][0], acc0[i][1], acc0[i][2], acc0[i][3]);
            *reinterpret_cast<float4*>(&h2[(size_t)gr * 128 + 64 + tx * 4]) =
                make_float4(acc1[i][0], acc1[i][1], acc1[i][2], acc1[i][3]);
        }
    }
}

// ---------------- attn coef layer 1: as1/ad1 [N,8] ----------------
__global__ __launch_bounds__(256) void attn1_k(const float* __restrict__ h1,
                                               const float* __restrict__ asrc,
                                               const float* __restrict__ adst,
                                               float* __restrict__ as1,
                                               float* __restrict__ ad1, int Nn) {
    int t = blockIdx.x * 256 + threadIdx.x;
    int n = t >> 3, h = t & 7;
    if (n >= Nn) return;
    const float* hp = h1 + (size_t)n * 64 + h * 8;
    float s = 0.f, d = 0.f;
#pragma unroll
    for (int c = 0; c < 8; ++c) {
        float v = hp[c];
        s += v * asrc[h * 8 + c];
        d += v * adst[h * 8 + c];
    }
    as1[(size_t)n * 8 + h] = s;
    ad1[(size_t)n * 8 + h] = d;
}

// ---------------- attn coef layer 2: as2/ad2 [N] ----------------
__global__ __launch_bounds__(256) void attn2_k(const float* __restrict__ h2,
                                               const float* __restrict__ asrc,
                                               const float* __restrict__ adst,
                                               float* __restrict__ as2,
                                               float* __restrict__ ad2, int Nn) {
    int wid = threadIdx.x >> 6, lane = threadIdx.x & 63;
    int n = blockIdx.x * 4 + wid;
    if (n >= Nn) return;
    float v0 = h2[(size_t)n * 128 + lane];
    float v1 = h2[(size_t)n * 128 + 64 + lane];
    float s = v0 * asrc[lane] + v1 * asrc[64 + lane];
    float d = v0 * adst[lane] + v1 * adst[64 + lane];
#pragma unroll
    for (int off = 32; off >= 1; off >>= 1) {
        s += __shfl_xor(s, off);
        d += __shfl_xor(d, off);
    }
    if (lane == 0) { as2[n] = s; ad2[n] = d; }
}

// ---------------- CSR build ----------------
__global__ __launch_bounds__(256) void hist_k(const int* __restrict__ ei, int E, int Etot,
                                              int* __restrict__ indeg) {
    int e = blockIdx.x * 256 + threadIdx.x;
    if (e >= Etot) return;
    int d = (e < E) ? ei[E + e] : (e - E);
    atomicAdd(&indeg[d], 1);
}

__global__ __launch_bounds__(256) void scanA_k(const int* __restrict__ indeg,
                                               int* __restrict__ indptr,
                                               int* __restrict__ bsums, int Nn) {
    __shared__ int sd[256];
    int t = threadIdx.x;
    int i0 = blockIdx.x * 2048 + t * 8;
    int v[8], ex[8];
    int run = 0;
#pragma unroll
    for (int j = 0; j < 8; ++j) {
        int i = i0 + j;
        v[j] = (i < Nn) ? indeg[i] : 0;
        ex[j] = run;
        run += v[j];
    }
    sd[t] = run;
    __syncthreads();
    for (int off = 1; off < 256; off <<= 1) {
        int a = (t >= off) ? sd[t - off] : 0;
        __syncthreads();
        sd[t] += a;
        __syncthreads();
    }
    int texc = sd[t] - run;
#pragma unroll
    for (int j = 0; j < 8; ++j) {
        int i = i0 + j;
        if (i < Nn) indptr[i] = texc + ex[j];
    }
    if (t == 0) bsums[blockIdx.x] = sd[255];
}

__global__ void scanB_k(int* __restrict__ bsums, int nb) {
    if (threadIdx.x == 0 && blockIdx.x == 0) {
        int run = 0;
        for (int b = 0; b < nb; ++b) {
            int x = bsums[b];
            bsums[b] = run;
            run += x;
        }
    }
}

__global__ __launch_bounds__(256) void scanC_k(int* __restrict__ indptr,
                                               const int* __restrict__ bsums,
                                               int* __restrict__ cursor, int Nn, int Etot) {
    int t = threadIdx.x;
    int b = blockIdx.x;
    int base = bsums[b];
    int i0 = b * 2048 + t * 8;
#pragma unroll
    for (int j = 0; j < 8; ++j) {
        int i = i0 + j;
        if (i < Nn) {
            int val = indptr[i] + base;
            indptr[i] = val;
            cursor[i] = val;
        }
    }
    if (b == 0 && t == 0) indptr[Nn] = Etot;
}

__global__ __launch_bounds__(256) void fill_k(const int* __restrict__ ei, int E, int Etot,
                                              int* __restrict__ cursor, int* __restrict__ col) {
    int e = blockIdx.x * 256 + threadIdx.x;
    if (e >= Etot) return;
    int s, d;
    if (e < E) { s = ei[e]; d = ei[E + e]; }
    else { s = e - E; d = e - E; }
    int pos = atomicAdd(&cursor[d], 1);
    col[pos] = s;
}

// ---------------- aggregation layer 1 (8 heads x 8 ch) + bias + ELU ----------------
__global__ __launch_bounds__(256) void agg1_k(const float* __restrict__ h1,
                                              const float* __restrict__ as1,
                                              const float* __restrict__ ad1,
                                              const int* __restrict__ indptr,
                                              const int* __restrict__ col,
                                              const float* __restrict__ b1,
                                              float* __restrict__ h1a, int Nn) {
    int wid = threadIdx.x >> 6, lane = threadIdx.x & 63;
    int n = blockIdx.x * 4 + wid;
    if (n >= Nn) return;
    int beg = indptr[n], end = indptr[n + 1];
    int h = lane & 7, eo = lane >> 3;
    float adn = ad1[(size_t)n * 8 + h];
    float ss = 0.f;
    for (int i = beg + eo; i < end; i += 8) {
        int s = col[i];
        ss += __expf(lrelu(as1[(size_t)s * 8 + h] + adn));
    }
    ss += __shfl_xor(ss, 8);
    ss += __shfl_xor(ss, 16);
    ss += __shfl_xor(ss, 32);
    int hb = lane >> 3;
    float sb = __shfl(ss, hb);
    float ab = __shfl(adn, hb);
    float inv = 1.f / sb;
    const float* __restrict__ h1l = h1 + lane;
    float acc0 = 0.f, acc1 = 0.f, acc2 = 0.f, acc3 = 0.f;
    float acc4 = 0.f, acc5 = 0.f, acc6 = 0.f, acc7 = 0.f;
    int i = beg;
    for (; i + 8 <= end; i += 8) {
        int s0 = col[i], s1 = col[i + 1], s2 = col[i + 2], s3 = col[i + 3];
        int s4 = col[i + 4], s5 = col[i + 5], s6 = col[i + 6], s7 = col[i + 7];
        float w0 = __expf(lrelu(as1[(size_t)s0 * 8 + hb] + ab));
        float w1 = __expf(lrelu(as1[(size_t)s1 * 8 + hb] + ab));
        float w2 = __expf(lrelu(as1[(size_t)s2 * 8 + hb] + ab));
        float w3 = __expf(lrelu(as1[(size_t)s3 * 8 + hb] + ab));
        float w4 = __expf(lrelu(as1[(size_t)s4 * 8 + hb] + ab));
        float w5 = __expf(lrelu(as1[(size_t)s5 * 8 + hb] + ab));
        float w6 = __expf(lrelu(as1[(size_t)s6 * 8 + hb] + ab));
        float w7 = __expf(lrelu(as1[(size_t)s7 * 8 + hb] + ab));
        acc0 += w0 * h1l[(size_t)s0 * 64];
        acc1 += w1 * h1l[(size_t)s1 * 64];
        acc2 += w2 * h1l[(size_t)s2 * 64];
        acc3 += w3 * h1l[(size_t)s3 * 64];
        acc4 += w4 * h1l[(size_t)s4 * 64];
        acc5 += w5 * h1l[(size_t)s5 * 64];
        acc6 += w6 * h1l[(size_t)s6 * 64];
        acc7 += w7 * h1l[(size_t)s7 * 64];
    }
    for (; i < end; ++i) {
        int s = col[i];
        acc0 += __expf(lrelu(as1[(size_t)s * 8 + hb] + ab)) * h1l[(size_t)s * 64];
    }
    float o = (((acc0 + acc1) + (acc2 + acc3)) + ((acc4 + acc5) + (acc6 + acc7))) * inv + b1[lane];
    h1a[(size_t)n * 64 + lane] = o > 0.f ? o : expm1f(o);
}

// ---------------- aggregation layer 2 (1 head x 128 ch) + bias ----------------
__global__ __launch_bounds__(256) void agg2_k(const float* __restrict__ h2,
                                              const float* __restrict__ as2,
                                              const float* __restrict__ ad2,
                                              const int* __restrict__ indptr,
                                              const int* __restrict__ col,
                                              const float* __restrict__ b2,
                                              float* __restrict__ out, int Nn) {
    int wid = threadIdx.x >> 6, lane = threadIdx.x & 63;
    int n = blockIdx.x * 4 + wid;
    if (n >= Nn) return;
    int beg = indptr[n], end = indptr[n + 1];
    float adn = ad2[n];
    float ss = 0.f;
    for (int i = beg + lane; i < end; i += 64) {
        ss += __expf(lrelu(as2[col[i]] + adn));
    }
#pragma unroll
    for (int off = 32; off >= 1; off >>= 1) ss += __shfl_xor(ss, off);
    float inv = 1.f / ss;
    const float* __restrict__ h2l = h2 + lane;
    float a00 = 0.f, a01 = 0.f, a02 = 0.f, a03 = 0.f;
    float a04 = 0.f, a05 = 0.f, a06 = 0.f, a07 = 0.f;
    float a10 = 0.f, a11 = 0.f, a12 = 0.f, a13 = 0.f;
    float a14 = 0.f, a15 = 0.f, a16 = 0.f, a17 = 0.f;
    int i = beg;
    for (; i + 8 <= end; i += 8) {
        int s0 = col[i], s1 = col[i + 1], s2 = col[i + 2], s3 = col[i + 3];
        int s4 = col[i + 4], s5 = col[i + 5], s6 = col[i + 6], s7 = col[i + 7];
        float w0 = __expf(lrelu(as2[s0] + adn));
        float w1 = __expf(lrelu(as2[s1] + adn));
        float w2 = __expf(lrelu(as2[s2] + adn));
        float w3 = __expf(lrelu(as2[s3] + adn));
        float w4 = __expf(lrelu(as2[s4] + adn));
        float w5 = __expf(lrelu(as2[s5] + adn));
        float w6 = __expf(lrelu(as2[s6] + adn));
        float w7 = __expf(lrelu(as2[s7] + adn));
        a00 += w0 * h2l[(size_t)s0 * 128]; a10 += w0 * h2l[(size_t)s0 * 128 + 64];
        a01 += w1 * h2l[(size_t)s1 * 128]; a11 += w1 * h2l[(size_t)s1 * 128 + 64];
        a02 += w2 * h2l[(size_t)s2 * 128]; a12 += w2 * h2l[(size_t)s2 * 128 + 64];
        a03 += w3 * h2l[(size_t)s3 * 128]; a13 += w3 * h2l[(size_t)s3 * 128 + 64];
        a04 += w4 * h2l[(size_t)s4 * 128]; a14 += w4 * h2l[(size_t)s4 * 128 + 64];
        a05 += w5 * h2l[(size_t)s5 * 128]; a15 += w5 * h2l[(size_t)s5 * 128 + 64];
        a06 += w6 * h2l[(size_t)s6 * 128]; a16 += w6 * h2l[(size_t)s6 * 128 + 64];
        a07 += w7 * h2l[(size_t)s7 * 128]; a17 += w7 * h2l[(size_t)s7 * 128 + 64];
    }
    for (; i < end; ++i) {
        int s = col[i];
        float w = __expf(lrelu(as2[s] + adn));
        a00 += w * h2l[(size_t)s * 128];
        a10 += w * h2l[(size_t)s * 128 + 64];
    }
    float r0 = ((a00 + a01) + (a02 + a03)) + ((a04 + a05) + (a06 + a07));
    float r1 = ((a10 + a11) + (a12 + a13)) + ((a14 + a15) + (a16 + a17));
    out[(size_t)n * 128 + lane] = r0 * inv + b2[lane];
    out[(size_t)n * 128 + 64 + lane] = r1 * inv + b2[64 + lane];
}

extern "C" void kernel_launch(void* const* d_in, const int* in_sizes, int n_in,
                              void* d_out, int out_size, void* d_ws, size_t ws_size,
                              hipStream_t stream) {
    const float* x = (const float*)d_in[0];
    const int* ei = (const int*)d_in[1];
    const float* W1 = (const float*)d_in[2];
    const float* asrc1 = (const float*)d_in[3];
    const float* adst1 = (const float*)d_in[4];
    const float* b1 = (const float*)d_in[5];
    const float* W2 = (const float*)d_in[6];
    const float* asrc2 = (const float*)d_in[7];
    const float* adst2 = (const float*)d_in[8];
    const float* b2 = (const float*)d_in[9];
    float* out = (float*)d_out;

    const int Nn = NNODES;
    const int E = in_sizes[1] / 2;
    const int Etot = E + Nn;

    char* w = (char*)d_ws;
    auto alloc = [&](size_t bytes) {
        char* p = w;
        w += (bytes + 255) & ~(size_t)255;
        return p;
    };
    float* h1 = (float*)alloc((size_t)Nn * 64 * 4);
    float* h1a = (float*)alloc((size_t)Nn * 64 * 4);
    float* h2 = (float*)alloc((size_t)Nn * 128 * 4);
    float* as1 = (float*)alloc((size_t)Nn * 8 * 4);
    float* ad1 = (float*)alloc((size_t)Nn * 8 * 4);
    float* as2 = (float*)alloc((size_t)Nn * 4);
    float* ad2 = (float*)alloc((size_t)Nn * 4);
    int* indeg = (int*)alloc((size_t)(Nn + 1) * 4);
    int* indptr = (int*)alloc((size_t)(Nn + 1) * 4);
    int* cursor = (int*)alloc((size_t)Nn * 4);
    int* bsums = (int*)alloc(4096);
    int* col = (int*)alloc((size_t)Etot * 4);

    const int NBLK = (Nn + 2047) / 2048;

    hipMemsetAsync(indeg, 0, (size_t)Nn * 4, stream);
    gemm1_k<<<(Nn + 255) / 256, 256, 0, stream>>>(x, W1, h1, Nn);
    attn1_k<<<(Nn * 8 + 255) / 256, 256, 0, stream>>>(h1, asrc1, adst1, as1, ad1, Nn);
    hist_k<<<(Etot + 255) / 256, 256, 0, stream>>>(ei, E, Etot, indeg);
    scanA_k<<<NBLK, 256, 0, stream>>>(indeg, indptr, bsums, Nn);
    scanB_k<<<1, 64, 0, stream>>>(bsums, NBLK);
    scanC_k<<<NBLK, 256, 0, stream>>>(indptr, bsums, cursor, Nn, Etot);
    fill_k<<<(Etot + 255) / 256, 256, 0, stream>>>(ei, E, Etot, cursor, col);
    agg1_k<<<(Nn + 3) / 4, 256, 0, stream>>>(h1, as1, ad1, indptr, col, b1, h1a, Nn);
    gemm2_k<<<(Nn + 127) / 128, 256, 0, stream>>>(h1a, W2, h2, Nn);
    attn2_k<<<(Nn + 3) / 4, 256, 0, stream>>>(h2, asrc2, adst2, as2, ad2, Nn);
    agg2_k<<<(Nn + 3) / 4, 256, 0, stream>>>(h2, as2, ad2, indptr, col, b2, out, Nn);
}